// Round 1
// 1121.171 us; speedup vs baseline: 1.2583x; 1.2583x over previous
//
#include <hip/hip_runtime.h>

typedef unsigned int u32;
typedef unsigned short u16;
typedef unsigned long long u64;
typedef _Float16 h2 __attribute__((ext_vector_type(2)));
typedef _Float16 h8 __attribute__((ext_vector_type(8)));
typedef float f4 __attribute__((ext_vector_type(4)));

#define ROWS 65536   // B*A
#define NB 1024
#define NA 64

__device__ __forceinline__ float dot4(float4 w, float4 x){
  return w.x*x.x + w.y*x.y + w.z*x.z + w.w*x.w;
}
__device__ __forceinline__ h2 u32_h2(u32 v){ union { u32 u; h2 h; } x; x.u = v; return x.h; }
__device__ __forceinline__ h2 pack_h2(float a, float b){ h2 r; r.x = (_Float16)a; r.y = (_Float16)b; return r; }
// fast sigmoid/tanh on v_exp_f32 + v_rcp_f32 (~1 ulp each; threshold is 1.1e-2)
__device__ __forceinline__ float fsig(float z){
  float e = __builtin_amdgcn_exp2f(-1.44269504f * z);
  return __builtin_amdgcn_rcpf(1.0f + e);
}
__device__ __forceinline__ float ftanh(float z){
  float e = __builtin_amdgcn_exp2f(2.885390082f * z);
  return 1.0f - 2.0f * __builtin_amdgcn_rcpf(1.0f + e);
}

// ---------------- actor_1 + attention: 8 rows per block, 128 threads ----------------
__global__ __launch_bounds__(128) void k_actor1(
    const float* __restrict__ obs, const float* __restrict__ w1, const float* __restrict__ b1,
    const float* __restrict__ lng, const float* __restrict__ lnb,
    const float* __restrict__ w2, const float* __restrict__ b2,
    const float* __restrict__ aw1, const float* __restrict__ ab1,
    const float* __restrict__ aw2, const float* __restrict__ ab2,
    const float* __restrict__ aw3, const float* __restrict__ ab3,
    float* __restrict__ thoughts, int* __restrict__ isinit)
{
  const int b0 = blockIdx.x * 8;
  const int t = threadIdx.x;
  __shared__ float4 xs[8][64];     // 8 obs rows (256 f32 each)
  __shared__ float hs[8][128];     // relu(LN(h))
  __shared__ float tb[8][128];     // thoughts
  __shared__ float ab[8][64];
  __shared__ float a2b[8][64];
  __shared__ float red[8][4];

  { const float4* og = (const float4*)(obs + (size_t)b0 * 256);
    #pragma unroll
    for (int j = 0; j < 4; j++){ int p = j * 128 + t; xs[p >> 6][p & 63] = og[p]; } }
  __syncthreads();

  // h = obs @ W1^T + b1   (thread t owns output feature t, streams W1 row t)
  float acc[8];
  #pragma unroll
  for (int r = 0; r < 8; r++) acc[r] = b1[t];
  { const float4* wr = (const float4*)(w1 + (size_t)t * 256);
    for (int j = 0; j < 64; j++){
      float4 w = wr[j];
      #pragma unroll
      for (int r = 0; r < 8; r++) acc[r] += dot4(w, xs[r][j]);
    } }

  // LayerNorm over 128 features (block = 2 waves)
  #pragma unroll
  for (int r = 0; r < 8; r++){
    float s = acc[r], s2 = acc[r] * acc[r];
    #pragma unroll
    for (int off = 32; off > 0; off >>= 1){ s += __shfl_down(s, off); s2 += __shfl_down(s2, off); }
    if ((t & 63) == 0){ red[r][t >> 6] = s; red[r][2 + (t >> 6)] = s2; }
  }
  __syncthreads();
  const float g_ = lng[t], bb_ = lnb[t];
  #pragma unroll
  for (int r = 0; r < 8; r++){
    float mu  = (red[r][0] + red[r][1]) * (1.0f/128.0f);
    float var = (red[r][2] + red[r][3]) * (1.0f/128.0f) - mu * mu;
    hs[r][t] = fmaxf((acc[r] - mu) * rsqrtf(var + 1e-5f) * g_ + bb_, 0.0f);
  }
  __syncthreads();

  // thoughts = relu(h) @ W2^T + b2
  float acc2[8];
  #pragma unroll
  for (int r = 0; r < 8; r++) acc2[r] = b2[t];
  { const float4* wr = (const float4*)(w2 + (size_t)t * 128);
    for (int j = 0; j < 32; j++){
      float4 w = wr[j];
      #pragma unroll
      for (int r = 0; r < 8; r++) acc2[r] += dot4(w, ((const float4*)hs[r])[j]);
    } }
  #pragma unroll
  for (int r = 0; r < 8; r++){
    thoughts[(size_t)(b0 + r) * 128 + t] = acc2[r];
    tb[r][t] = acc2[r];
  }
  __syncthreads();

  // attention MLP
  if (t < 64){
    float a[8];
    #pragma unroll
    for (int r = 0; r < 8; r++) a[r] = ab1[t];
    const float4* wr = (const float4*)(aw1 + (size_t)t * 128);
    for (int j = 0; j < 32; j++){
      float4 w = wr[j];
      #pragma unroll
      for (int r = 0; r < 8; r++) a[r] += dot4(w, ((const float4*)tb[r])[j]);
    }
    #pragma unroll
    for (int r = 0; r < 8; r++) ab[r][t] = fmaxf(a[r], 0.0f);
  }
  __syncthreads();
  if (t < 64){
    float a[8];
    #pragma unroll
    for (int r = 0; r < 8; r++) a[r] = ab2[t];
    const float4* wr = (const float4*)(aw2 + (size_t)t * 64);
    for (int j = 0; j < 16; j++){
      float4 w = wr[j];
      #pragma unroll
      for (int r = 0; r < 8; r++) a[r] += dot4(w, ((const float4*)ab[r])[j]);
    }
    #pragma unroll
    for (int r = 0; r < 8; r++) a2b[r][t] = fmaxf(a[r], 0.0f);
  }
  __syncthreads();
  if (t < 8){
    float p = ab3[0];
    for (int j = 0; j < 64; j++) p += aw3[j] * a2b[t][j];
    isinit[b0 + t] = (p > 0.0f) ? 1 : 0;   // sigmoid(p) > 0.5  <=>  p > 0
  }
}

// ---------------- K-nearest groups: one block per batch ----------------
__global__ __launch_bounds__(256) void k_groups(
    const float* __restrict__ thoughts, int* __restrict__ idxout)
{
  const int b = blockIdx.x;
  const int tid = threadIdx.x;
  __shared__ float T[64 * 130];
  __shared__ float sq[64];
  for (int p = tid; p < 8192; p += 256){
    T[(p >> 7) * 130 + (p & 127)] = thoughts[(size_t)b * 8192 + p];
  }
  __syncthreads();
  if (tid < 64){
    const float2* tj = (const float2*)&T[tid * 130];
    float s = 0.0f;
    #pragma unroll 8
    for (int k = 0; k < 64; k++){ float2 v = tj[k]; s += v.x*v.x + v.y*v.y; }
    sq[tid] = s;
  }
  __syncthreads();
  const int lane = tid & 63;
  const int wv = tid >> 6;
  const float2* tj = (const float2*)&T[lane * 130];
  const float sqj = sq[lane];
  for (int ii = 0; ii < 16; ii++){
    const int i = wv * 16 + ii;
    const float2* ti = (const float2*)&T[i * 130];
    float dot = 0.0f;
    #pragma unroll 8
    for (int k = 0; k < 64; k++){ float2 a = ti[k]; float2 c = tj[k]; dot += a.x*c.x + a.y*c.y; }
    float d = fmaxf(sq[i] + sqj - 2.0f*dot, 0.0f);   // clamp keeps uint-compare == float-compare
    u64 key = (((u64)__float_as_uint(d)) << 32) | (u32)lane;
    u64 mask = 0;
    for (int q = 0; q < 8; q++){
      u64 m = key;
      #pragma unroll
      for (int off = 32; off > 0; off >>= 1){ u64 o = __shfl_xor(m, off); if (o < m) m = o; }
      mask |= 1ull << (u32)(m & 63u);
      if (key == m) key = ~0ull;
    }
    if (lane == 0){
      u64 mm = mask;
      int base = (b * 64 + i) * 8;
      #pragma unroll
      for (int q = 0; q < 8; q++){ int j = (int)__builtin_ctzll(mm); mm &= mm - 1; idxout[base + q] = j; }
    }
  }
}

// ---------------- sequential gather -> bi-LSTM -> scatter: one block per batch ----------------
// 512 threads: tid = dir(1b) | h-row l(6b) | K-quarter q(2b).
// v2: the Wih input projection (2/3 of the old per-step VALU work) is HOISTED out of the
// sequential recurrence into a per-initiator MFMA GEMM on the matrix pipe:
//   Zx[dir][t][l][g] = bias + X[t] @ Wih[dir][g*64+l]   (8x128 @ 128x512, K=128)
// done as v_mfma_f32_16x16x32_f16, one (dir,gate) 64-col slice per wave (M=16: rows 8..15 of
// X16 are zeros). Both A (X16) and B (Bf regs, replacing the old wi[] array -> same 64 VGPR)
// are packed with the SAME k-convention (k = kt*32 + (lane>>4)*8 + j), so the result only
// relies on the verified mappings: A row = lane&15, B col = lane&15,
// C: col = lane&15, row = (lane>>4)*4 + reg  (valid timesteps t<8 live in lanes 0..31).
// X16 rows padded to 136 f16 so A-fragment ds_read_b128 is ~conflict-free.
// The sequential 8-step loop keeps only the 64-dim Whh*h quarter-dots (32 fdot2/thread/step,
// was 96) + shuffle combine + gates; structure (barriers, hb16, nt writes) unchanged.
__global__ __launch_bounds__(512, 4) void k_scan(
    const float* __restrict__ thoughts, const int* __restrict__ isinit, const int* __restrict__ idx,
    const float* __restrict__ wihf, const float* __restrict__ whhf,
    const float* __restrict__ bihf, const float* __restrict__ bhhf,
    const float* __restrict__ wihb, const float* __restrict__ whhb,
    const float* __restrict__ bihb, const float* __restrict__ bhhb,
    float* __restrict__ newt)
{
  const int b    = blockIdx.x;
  const int tid  = threadIdx.x;
  const int dir  = tid >> 8;          // 0 fwd, 1 bwd (== wave>>2)
  const int l    = (tid >> 2) & 63;   // h index (phase B)
  const int q    = tid & 3;           // K quarter (phase B)
  const int lane = tid & 63;
  const int g    = (tid >> 6) & 3;    // gate owned by this wave (phase A)

  __shared__ float nt[64 * 128];                     // 32 KB state
  __shared__ __align__(16) _Float16 X16[16 * 136];   // gathered X (f16), rows 8..15 zero, padded
  __shared__ __align__(16) float Zx[2 * 8 * 64 * 4]; // hoisted input projection (+bias), 16 KB
  __shared__ __align__(16) _Float16 hb16[2][64];     // h state (f16)
  __shared__ int gall[512];
  __shared__ int flags[64];

  const float* whh = dir ? whhb : whhf;

  // ---- B fragments: Wih rows (g*64 + ni*16 + lane&15), k = kt*32 + (lane>>4)*8 + j ----
  h8 Bf[4][4];
  {
    const float* wihd = dir ? wihb : wihf;
    const int lr = lane & 15, hi = lane >> 4;
    #pragma unroll
    for (int ni = 0; ni < 4; ni++){
      const float* wr = wihd + (size_t)((g << 6) + (ni << 4) + lr) * 128 + (hi << 3);
      #pragma unroll
      for (int kt = 0; kt < 4; kt++){
        float4 wlo = *(const float4*)(wr + kt * 32);
        float4 whi = *(const float4*)(wr + kt * 32 + 4);
        h8 bf;
        bf[0] = (_Float16)wlo.x; bf[1] = (_Float16)wlo.y; bf[2] = (_Float16)wlo.z; bf[3] = (_Float16)wlo.w;
        bf[4] = (_Float16)whi.x; bf[5] = (_Float16)whi.y; bf[6] = (_Float16)whi.z; bf[7] = (_Float16)whi.w;
        Bf[ni][kt] = bf;
      }
    }
  }
  // bias for the columns this lane will write (bih+bhh counted once, folded into Zx)
  float biasl[4];
  {
    const float* bihd = dir ? bihb : bihf;
    const float* bhhd = dir ? bhhb : bhhf;
    #pragma unroll
    for (int ni = 0; ni < 4; ni++){
      int n = (g << 6) + (ni << 4) + (lane & 15);
      biasl[ni] = bihd[n] + bhhd[n];
    }
  }

  // ---- Whh quarter-rows for the recurrence (unchanged) ----
  h2 wh[4][8];    // whh[gg*64+l, q*16 .. q*16+16)
  #pragma unroll
  for (int gg = 0; gg < 4; gg++){
    const float2* wp = (const float2*)(whh + (size_t)(gg * 64 + l) * 64 + q * 16);
    #pragma unroll
    for (int j = 0; j < 8; j++){ float2 w = wp[j]; wh[gg][j] = pack_h2(w.x, w.y); }
  }

  for (int p = tid; p < 8192; p += 512) nt[p] = thoughts[(size_t)b * 8192 + p];
  for (int p = tid; p < 544; p += 512) ((h2*)X16)[544 + p] = pack_h2(0.0f, 0.0f);  // zero rows 8..15
  gall[tid] = idx[(size_t)b * 512 + tid];
  if (tid < 64) flags[tid] = isinit[b * 64 + tid];
  __syncthreads();

  #pragma unroll 1
  for (int i = 0; i < 64; i++){
    if (!flags[i]) continue;            // uniform across block
    const int* gi = &gall[i * 8];
    { const int t = tid >> 6, cc = tid & 63;      // snapshot X -> f16 (1 h2/thread)
      float2 v = *(const float2*)&nt[gi[t] * 128 + 2 * cc];
      *(h2*)&X16[t * 136 + 2 * cc] = pack_h2(v.x, v.y); }
    __syncthreads();

    // ---- phase A: Zx = bias + X @ Wih^T  (matrix pipe) ----
    {
      const int lr = lane & 15, hi = lane >> 4;
      const int aoff = lr * 136 + (hi << 3);
      #pragma unroll
      for (int ni = 0; ni < 4; ni++){
        f4 acc = {0.0f, 0.0f, 0.0f, 0.0f};
        #pragma unroll
        for (int kt = 0; kt < 4; kt++){
          h8 a = *(const h8*)&X16[aoff + kt * 32];
          acc = __builtin_amdgcn_mfma_f32_16x16x32_f16(a, Bf[ni][kt], acc, 0, 0, 0);
        }
        if (lane < 32){
          const int t0 = hi << 2, lp = (ni << 4) + lr;
          #pragma unroll
          for (int r = 0; r < 4; r++)
            Zx[(((dir << 3) + t0 + r) * 64 + lp) * 4 + g] = acc[r] + biasl[ni];
        }
      }
    }
    __syncthreads();

    // ---- phase B: 8-step recurrence, Whh part only ----
    float c = 0.0f;
    #pragma unroll 1
    for (int s = 0; s < 8; s++){
      const int tt = dir ? (7 - s) : s;
      float z0, z1, z2, z3;
      if (q == 0){
        const float4 zx = *(const float4*)&Zx[(((dir << 3) + tt) * 64 + l) * 4];
        z0 = zx.x; z1 = zx.y; z2 = zx.z; z3 = zx.w;
      } else { z0 = 0.0f; z1 = 0.0f; z2 = 0.0f; z3 = 0.0f; }
      if (s > 0){
        const uint4* Hq = (const uint4*)&hb16[dir][q * 16];
        #pragma unroll
        for (int j = 0; j < 2; j++){
          uint4 h = Hq[j];
          z0 = __builtin_amdgcn_fdot2(wh[0][4*j+0], u32_h2(h.x), z0, false);
          z0 = __builtin_amdgcn_fdot2(wh[0][4*j+1], u32_h2(h.y), z0, false);
          z0 = __builtin_amdgcn_fdot2(wh[0][4*j+2], u32_h2(h.z), z0, false);
          z0 = __builtin_amdgcn_fdot2(wh[0][4*j+3], u32_h2(h.w), z0, false);
          z1 = __builtin_amdgcn_fdot2(wh[1][4*j+0], u32_h2(h.x), z1, false);
          z1 = __builtin_amdgcn_fdot2(wh[1][4*j+1], u32_h2(h.y), z1, false);
          z1 = __builtin_amdgcn_fdot2(wh[1][4*j+2], u32_h2(h.z), z1, false);
          z1 = __builtin_amdgcn_fdot2(wh[1][4*j+3], u32_h2(h.w), z1, false);
          z2 = __builtin_amdgcn_fdot2(wh[2][4*j+0], u32_h2(h.x), z2, false);
          z2 = __builtin_amdgcn_fdot2(wh[2][4*j+1], u32_h2(h.y), z2, false);
          z2 = __builtin_amdgcn_fdot2(wh[2][4*j+2], u32_h2(h.z), z2, false);
          z2 = __builtin_amdgcn_fdot2(wh[2][4*j+3], u32_h2(h.w), z2, false);
          z3 = __builtin_amdgcn_fdot2(wh[3][4*j+0], u32_h2(h.x), z3, false);
          z3 = __builtin_amdgcn_fdot2(wh[3][4*j+1], u32_h2(h.y), z3, false);
          z3 = __builtin_amdgcn_fdot2(wh[3][4*j+2], u32_h2(h.z), z3, false);
          z3 = __builtin_amdgcn_fdot2(wh[3][4*j+3], u32_h2(h.w), z3, false);
        } }
      // combine the 4 K-quarters (adjacent lanes, same wave)
      z0 += __shfl_xor(z0, 1); z0 += __shfl_xor(z0, 2);
      z1 += __shfl_xor(z1, 1); z1 += __shfl_xor(z1, 2);
      z2 += __shfl_xor(z2, 1); z2 += __shfl_xor(z2, 2);
      z3 += __shfl_xor(z3, 1); z3 += __shfl_xor(z3, 2);
      // gates thread-local (i,f,g,o); c redundant-consistent across the 4 q-lanes
      float fi = fsig(z0);
      float ff = fsig(z1);
      float fg = ftanh(z2);
      float fo = fsig(z3);
      c = ff * c + fi * fg;
      float hn = fo * ftanh(c);
      if (q == 0){
        hb16[dir][l] = (_Float16)hn;
        nt[gi[tt] * 128 + dir * 64 + l] = hn;
      }
      __syncthreads();
    }
  }
  for (int p = tid; p < 8192; p += 512) newt[(size_t)b * 8192 + p] = nt[p];
}

// ---------------- actor_2: 8 rows per block, 128 threads ----------------
__global__ __launch_bounds__(128) void k_actor2(
    const float* __restrict__ thoughts, const float* __restrict__ newt,
    const float* __restrict__ w1, const float* __restrict__ b1, const float* __restrict__ w2,
    float* __restrict__ out)
{
  const int b0 = blockIdx.x * 8;
  const int t = threadIdx.x;
  __shared__ float xs[8][256];
  __shared__ float ybuf[8][128];
  for (int p = t; p < 2048; p += 128){
    int r = p >> 8, c = p & 255;
    float v = (c < 128) ? thoughts[(size_t)(b0 + r) * 128 + c]
                        : newt[(size_t)(b0 + r) * 128 + (c - 128)];
    xs[r][c] = fmaxf(v, 0.0f);
  }
  __syncthreads();
  float acc[8];
  #pragma unroll
  for (int r = 0; r < 8; r++) acc[r] = b1[t];
  { const float4* wr = (const float4*)(w1 + (size_t)t * 256);
    for (int j = 0; j < 64; j++){
      float4 w = wr[j];
      #pragma unroll
      for (int r = 0; r < 8; r++) acc[r] += dot4(w, ((const float4*)xs[r])[j]);
    } }
  #pragma unroll
  for (int r = 0; r < 8; r++) ybuf[r][t] = acc[r];
  __syncthreads();
  if (t < 64){
    float a[8];
    #pragma unroll
    for (int r = 0; r < 8; r++) a[r] = 0.0f;
    const float4* wr = (const float4*)(w2 + (size_t)t * 128);
    for (int j = 0; j < 32; j++){
      float4 w = wr[j];
      #pragma unroll
      for (int r = 0; r < 8; r++) a[r] += dot4(w, ((const float4*)ybuf[r])[j]);
    }
    #pragma unroll
    for (int r = 0; r < 8; r++) out[(size_t)(b0 + r) * 64 + t] = ftanh(a[r]);
  }
}

extern "C" void kernel_launch(void* const* d_in, const int* in_sizes, int n_in,
                              void* d_out, int out_size, void* d_ws, size_t ws_size,
                              hipStream_t stream)
{
  const float* obs  = (const float*)d_in[0];
  const float* w1   = (const float*)d_in[1];
  const float* b1   = (const float*)d_in[2];
  const float* lng  = (const float*)d_in[3];
  const float* lnb  = (const float*)d_in[4];
  const float* w2   = (const float*)d_in[5];
  const float* b2   = (const float*)d_in[6];
  const float* aw1  = (const float*)d_in[7];
  const float* ab1  = (const float*)d_in[8];
  const float* aw2  = (const float*)d_in[9];
  const float* ab2  = (const float*)d_in[10];
  const float* aw3  = (const float*)d_in[11];
  const float* ab3  = (const float*)d_in[12];
  const float* wihf = (const float*)d_in[13];
  const float* whhf = (const float*)d_in[14];
  const float* bihf = (const float*)d_in[15];
  const float* bhhf = (const float*)d_in[16];
  const float* wihb = (const float*)d_in[17];
  const float* whhb = (const float*)d_in[18];
  const float* bihb = (const float*)d_in[19];
  const float* bhhb = (const float*)d_in[20];
  const float* a2w1 = (const float*)d_in[21];
  const float* a2b1 = (const float*)d_in[22];
  const float* a2w2 = (const float*)d_in[23];

  float* thoughts = (float*)d_ws;                       // 33.5 MB
  float* newt     = thoughts + (size_t)ROWS * 128;      // 33.5 MB
  int*   isinit   = (int*)(newt + (size_t)ROWS * 128);  // 256 KB
  int*   idxb     = isinit + ROWS;                      // 2 MB

  hipLaunchKernelGGL(k_actor1, dim3(ROWS / 8), dim3(128), 0, stream,
                     obs, w1, b1, lng, lnb, w2, b2, aw1, ab1, aw2, ab2, aw3, ab3,
                     thoughts, isinit);
  hipLaunchKernelGGL(k_groups, dim3(NB), dim3(256), 0, stream, thoughts, idxb);
  hipLaunchKernelGGL(k_scan, dim3(NB), dim3(512), 0, stream,
                     thoughts, isinit, idxb,
                     wihf, whhf, bihf, bhhf, wihb, whhb, bihb, bhhb, newt);
  hipLaunchKernelGGL(k_actor2, dim3(ROWS / 8), dim3(128), 0, stream,
                     thoughts, newt, a2w1, a2b1, a2w2, (float*)d_out);
}